// Round 16
// baseline (8207.893 us; speedup 1.0000x reference)
//
#include <hip/hip_runtime.h>
#include <stdint.h>

typedef unsigned long long u64;

#define VOCAB 128
#define RD 128
#define DM 1024
#define NFF 6
#define BATCH 64
#define TSTEPS 512

// ---------------------------------------------------------------------------
// ws layout (bytes): (identical to r15)
//   [0, 786432)       ffs  [L][half][q][c][2] u64:
//                     u64 idx = (((L*2+half)*8+q)*512 + c)*2 + s
//                     (word-pair q of column half*512+c)
//   [786432, +2048)   ebits [v][2] u64
//   [788480, +2048)   headb [v][2] u64
//   [790528, +512)    losses [64] double
// ---------------------------------------------------------------------------
#define OFF_EB    786432
#define OFF_HB    788480
#define OFF_LOSS  790528

typedef const __attribute__((address_space(1))) void* gas1_t;
typedef __attribute__((address_space(3))) void*       las3_t;

// Pack ff sign bits. bit b of word (L,w,j) = (ff[L][w*64+b][j] < 0)  (1 => -1)
__global__ void pack_ff(const float* __restrict__ ff, u64* __restrict__ ffs) {
    int wid  = blockIdx.x * (blockDim.x >> 6) + (threadIdx.x >> 6); // 0..1535
    int lane = threadIdx.x & 63;
    int jt = wid & 15;
    int w  = (wid >> 4) & 15;  // word 0..15
    int L  = wid >> 8;         // layer
    int j  = jt * 64 + lane;   // column
    const float* src = ff + ((size_t)(L * DM) + w * 64) * DM + j;
    u64 word = 0;
#pragma unroll
    for (int b = 0; b < 64; ++b) {
        float v = src[(size_t)b * DM];
        word |= (u64)(v < 0.0f) << b;
    }
    int half = j >> 9, c = j & 511, q = w >> 1, s = w & 1;
    ffs[((((L * 2 + half) * 8 + q) * 512 + c) << 1) + s] = word;
}

// Pack embed rows and head columns (tiny).
__global__ void pack_small(const float* __restrict__ emb, const float* __restrict__ head,
                           u64* __restrict__ eb, u64* __restrict__ hb) {
    int tid = threadIdx.x; // 0..255
    if (tid < 128) {
        int v = tid;
        for (int wd = 0; wd < 2; ++wd) {
            u64 word = 0;
            for (int l = 0; l < 64; ++l)
                word |= (u64)(emb[v * RD + wd * 64 + l] < 0.0f) << l;
            eb[v * 2 + wd] = word;
        }
    } else {
        int v = tid - 128;
        for (int wd = 0; wd < 2; ++wd) {
            u64 word = 0;
            for (int l = 0; l < 64; ++l)
                word |= (u64)(head[(wd * 64 + l) * VOCAB + v] < 0.0f) << l;
            hb[v * 2 + wd] = word;
        }
    }
}

// Relay-staged main kernel: one block (one CU) per batch row, 1024 threads
// (4 waves/SIMD). Weights stream L2 -> LDS via global_load_lds into two
// 64 KB half-layer buffers; per stage, one thread-half computes while the
// other stages ITS OWN next buffer and drains its own vmcnt (overlap is
// role-structural, immune to barrier-drain semantics). ~45 VGPRs: nothing
// for the allocator to spill.
__global__ void __launch_bounds__(1024, 1)
brnn_main(const int* __restrict__ tokens,
          const float* __restrict__ initial_lat,
          const float* __restrict__ thr_lat,
          const u64* __restrict__ ffs,
          const u64* __restrict__ eb,
          const u64* __restrict__ hb,
          double* __restrict__ losses)
{
    const int b    = blockIdx.x;
    const int tid  = threadIdx.x;
    const int lane = tid & 63;
    const int wv   = tid >> 6;   // 0..15
    const int w8   = wv & 7;     // wave index within half
    const int half = tid >> 9;   // 0 or 1

    __shared__ __align__(16) u64 wbuf[2][8][512][2]; // 2 x 64 KB half-layer buffers
    __shared__ __align__(16) u64 hx[2][16];
    __shared__ u64 hbL[2 * VOCAB];

    if (tid < 2 * VOCAB) hbL[tid] = hb[tid];

    // thresholds for THIS thread's column (col == tid): bit(-1) <=> acc >= cthr
    int cthr[NFF];
#pragma unroll
    for (int L = 0; L < NFF; ++L) {
        int th = (int)rintf(thr_lat[L * DM + tid]); // round-half-even == jnp.round
        cthr[L] = ((DM - th) >> 1) + 1;
    }

    // init h = sign(initial_lat) into hx[0] (16 waves -> 16 words)
    {
        u64 m = __ballot(initial_lat[tid] < 0.0f);
        if (lane == 0) hx[0][wv] = m;
    }

    // prologue: half 0 stages stage 0 (layer 0, cols 0-511) into wbuf[0]
    if (half == 0) {
#pragma unroll
        for (int k = 0; k < 8; ++k) {
            const u64* gp = ffs + ((size_t)(k * 512 + w8 * 64 + lane) << 1);
            __builtin_amdgcn_global_load_lds((gas1_t)gp,
                                             (las3_t)&wbuf[0][k][w8 * 64][0], 16, 0, 0);
        }
        asm volatile("s_waitcnt vmcnt(0)" ::: "memory");
    }
    __syncthreads();

    const int* toks = tokens + b * TSTEPS;
    double lacc = 0.0;

    for (int t = 0; t < TSTEPS; ++t) {
        const int tok = toks[t]; // uniform -> scalar load
        u64 enew = 0;
        if (wv == 0 && lane < 2) enew = eb[tok * 2 + lane]; // prefetch for splice

        // --- 12 stages: (L, hf) = (s>>1, s&1); compute half hf, other stages s+1 ---
#pragma unroll
        for (int s = 0; s < 12; ++s) {
            const int L  = s >> 1, hf = s & 1;
            const int s1 = (s + 1) % 12;          // stage to prefetch (wraps to next t)
            const int L1 = s1 >> 1, hf1 = s1 & 1; // hf1 == stager's own half
            if (half == hf) {
                // compute column `tid` of layer L from my buffer
                const ulonglong2* hp = (const ulonglong2*)hx[L & 1];
                int acc = 0;
#pragma unroll
                for (int q = 0; q < 8; ++q) {
                    ulonglong2 hv = hp[q];                       // broadcast b128
                    ulonglong2 w  = *(const ulonglong2*)wbuf[hf][q][tid & 511];
                    acc += __popcll(hv.x ^ w.x) + __popcll(hv.y ^ w.y);
                }
                u64 m = __ballot(acc >= cthr[L]);
                if (lane == 0) hx[(L + 1) & 1][hf * 8 + w8] = m;
            } else {
                // stage s1 (my half's next work) into my buffer wbuf[hf1]
#pragma unroll
                for (int k = 0; k < 8; ++k) {
                    const u64* gp = ffs +
                        ((size_t)((((L1 * 2 + hf1) * 8 + k) * 512) + w8 * 64 + lane) << 1);
                    __builtin_amdgcn_global_load_lds((gas1_t)gp,
                                                     (las3_t)&wbuf[hf1][k][w8 * 64][0],
                                                     16, 0, 0);
                }
                asm volatile("s_waitcnt vmcnt(0)" ::: "memory"); // drain in MY slot
            }
            __syncthreads();
        }

        // --- head + log-softmax + loss + embed splice (wave 0); h5 in hx[0] ---
        if (wv == 0) {
            u64 ra = hx[0][14], rb = hx[0][15];
            u64 h0a = hbL[lane * 2 + 0],        h0b = hbL[lane * 2 + 1];
            u64 h1a = hbL[(lane + 64) * 2 + 0], h1b = hbL[(lane + 64) * 2 + 1];
            int d0 = 128 - 2 * (__popcll(ra ^ h0a) + __popcll(rb ^ h0b));
            int d1 = 128 - 2 * (__popcll(ra ^ h1a) + __popcll(rb ^ h1b));
            float l0 = (float)d0 * (1.0f / 16.0f);
            float l1 = (float)d1 * (1.0f / 16.0f);
            float mx = fmaxf(l0, l1);
#pragma unroll
            for (int sh = 32; sh >= 1; sh >>= 1) mx = fmaxf(mx, __shfl_xor(mx, sh));
            float se = __expf(l0 - mx) + __expf(l1 - mx);
#pragma unroll
            for (int sh = 32; sh >= 1; sh >>= 1) se += __shfl_xor(se, sh);
            int   tl   = tok & 63;
            float la   = __shfl(l0, tl);
            float lb   = __shfl(l1, tl);
            float ltok = (tok >> 6) ? lb : la;
            lacc += (double)(mx + __logf(se) - ltok);
            // splice x_new read-part = sign(embed[tok]) into words 14,15
            if (lane < 2) hx[0][14 + lane] = enew;
        }
        __syncthreads();
    }

    if (tid == 0) losses[b] = lacc;
}

__global__ void reduce_loss(const double* __restrict__ losses, float* __restrict__ out) {
    int lane = threadIdx.x; // 64 threads, 1 wave
    double v = losses[lane];
#pragma unroll
    for (int sh = 32; sh >= 1; sh >>= 1) v += __shfl_down(v, sh);
    if (lane == 0) out[0] = (float)(v * (1.0 / ((double)BATCH * (double)TSTEPS)));
}

extern "C" void kernel_launch(void* const* d_in, const int* in_sizes, int n_in,
                              void* d_out, int out_size, void* d_ws, size_t ws_size,
                              hipStream_t stream) {
    const int*   tokens  = (const int*)d_in[0];   // (64, 512) int32
    const float* initial = (const float*)d_in[1]; // (1024,)
    const float* embed   = (const float*)d_in[2]; // (128, 128)
    const float* ff      = (const float*)d_in[3]; // (6, 1024, 1024)
    const float* head    = (const float*)d_in[4]; // (128, 128)
    const float* thrl    = (const float*)d_in[5]; // (6, 1024)

    char* ws = (char*)d_ws;
    u64*    ffs    = (u64*)ws;                 // 786432 B
    u64*    eb     = (u64*)(ws + OFF_EB);      // 2048 B
    u64*    hb     = (u64*)(ws + OFF_HB);      // 2048 B
    double* losses = (double*)(ws + OFF_LOSS); // 512 B

    pack_ff<<<384, 256, 0, stream>>>(ff, ffs);
    pack_small<<<1, 256, 0, stream>>>(embed, head, eb, hb);
    brnn_main<<<BATCH, 1024, 0, stream>>>(tokens, initial, thrl, ffs, eb, hb, losses);
    reduce_loss<<<1, 64, 0, stream>>>(losses, (float*)d_out);
}

// Round 17
// 5647.525 us; speedup vs baseline: 1.4534x; 1.4534x over previous
//
#include <hip/hip_runtime.h>
#include <stdint.h>

typedef unsigned long long u64;
typedef u64 u64x2 __attribute__((ext_vector_type(2)));

#define VOCAB 128
#define RD 128
#define DM 1024
#define NFF 6
#define BATCH 64
#define TSTEPS 512

// ---------------------------------------------------------------------------
// ws layout (bytes): (identical to r15, proven)
//   [0, 786432)       ffs  [L][half][q][c][2] u64:
//                     u64 idx = (((L*2+half)*8+q)*512 + c)*2 + s
//                     (word-pair q of column half*512+c)
//   [786432, +2048)   ebits [v][2] u64
//   [788480, +2048)   headb [v][2] u64
//   [790528, +512)    losses [64] double
// ---------------------------------------------------------------------------
#define OFF_EB    786432
#define OFF_HB    788480
#define OFF_LOSS  790528

// lgkm-only barrier: LDS h-writes drained; global weight loads (vmcnt)
// stay in flight across the barrier.
#define BARRIER()                                            \
    do {                                                     \
        asm volatile("s_waitcnt lgkmcnt(0)" ::: "memory");   \
        __builtin_amdgcn_s_barrier();                        \
    } while (0)

// Pack ff sign bits. bit b of word (L,w,j) = (ff[L][w*64+b][j] < 0)  (1 => -1)
__global__ void pack_ff(const float* __restrict__ ff, u64* __restrict__ ffs) {
    int wid  = blockIdx.x * (blockDim.x >> 6) + (threadIdx.x >> 6); // 0..1535
    int lane = threadIdx.x & 63;
    int jt = wid & 15;
    int w  = (wid >> 4) & 15;  // word 0..15
    int L  = wid >> 8;         // layer
    int j  = jt * 64 + lane;   // column
    const float* src = ff + ((size_t)(L * DM) + w * 64) * DM + j;
    u64 word = 0;
#pragma unroll
    for (int b = 0; b < 64; ++b) {
        float v = src[(size_t)b * DM];
        word |= (u64)(v < 0.0f) << b;
    }
    int half = j >> 9, c = j & 511, q = w >> 1, s = w & 1;
    ffs[((((L * 2 + half) * 8 + q) * 512 + c) << 1) + s] = word;
}

// Pack embed rows and head columns (tiny).
__global__ void pack_small(const float* __restrict__ emb, const float* __restrict__ head,
                           u64* __restrict__ eb, u64* __restrict__ hb) {
    int tid = threadIdx.x; // 0..255
    if (tid < 128) {
        int v = tid;
        for (int wd = 0; wd < 2; ++wd) {
            u64 word = 0;
            for (int l = 0; l < 64; ++l)
                word |= (u64)(emb[v * RD + wd * 64 + l] < 0.0f) << l;
            eb[v * 2 + wd] = word;
        }
    } else {
        int v = tid - 128;
        for (int wd = 0; wd < 2; ++wd) {
            u64 word = 0;
            for (int l = 0; l < 64; ++l)
                word |= (u64)(head[(wd * 64 + l) * VOCAB + v] < 0.0f) << l;
            hb[v * 2 + wd] = word;
        }
    }
}

// One streamed layer L (literal): consume p[] (this thread's column of layer
// L) and, PER WORD-PAIR, immediately re-issue that pair's load for layer PFL.
// Peak live registers stay ~34 (old pair dies right before new is defined),
// yet every load is in flight for a full layer before its next consume.
// h read from hx[L&1], ballot written to hx[(L+1)&1].
#define SLAYER(L, PFL)                                                     \
    do {                                                                   \
        const ulonglong2* hp_ = (const ulonglong2*)hx[(L) & 1];            \
        int acc_ = 0;                                                      \
        _Pragma("unroll")                                                  \
        for (int q_ = 0; q_ < 8; ++q_) {                                   \
            ulonglong2 hv_ = hp_[q_]; /* broadcast ds_read_b128 */         \
            acc_ += __popcll(hv_.x ^ p[2 * q_]) +                          \
                    __popcll(hv_.y ^ p[2 * q_ + 1]);                       \
            u64x2 v_ = wsrc[(((PFL) * 16 + (half << 3) + q_) << 9) + cc];  \
            p[2 * q_] = v_.x; p[2 * q_ + 1] = v_.y;                        \
        }                                                                  \
        u64 m_ = __ballot(acc_ >= cthr[L]);                                \
        if (lane == 0) hx[((L) + 1) & 1][wv] = m_;                         \
        BARRIER();                                                         \
    } while (0)

// Main recurrent kernel: one block (one CU) per batch row, 1024 threads
// (4 waves/SIMD -> real TLP to hide L2 latency). Layer 5 LDS-resident
// (128 KB); layers 0-4 streamed with single-buffer interleaved
// consume/reissue. Per-thread register ask ~56 <= the 64-grant.
__global__ void __launch_bounds__(1024, 1)
brnn_main(const int* __restrict__ tokens,
          const float* __restrict__ initial_lat,
          const float* __restrict__ thr_lat,
          const u64* __restrict__ ffs,
          const u64* __restrict__ eb,
          const u64* __restrict__ hb,
          double* __restrict__ losses)
{
    const int b    = blockIdx.x;
    const int tid  = threadIdx.x;
    const int lane = tid & 63;
    const int wv   = tid >> 6;   // 0..15
    const int half = tid >> 9;   // 0 or 1
    const int cc   = tid & 511;  // column within half

    __shared__ __align__(16) u64 wlds[8][1024][2]; // layer 5: 128 KB
    __shared__ __align__(16) u64 hx[2][16];
    __shared__ u64 hbL[2 * VOCAB];

    const u64x2* wsrc = (const u64x2*)ffs;

    // --- one-time: stage layer 5 into LDS (coalesced) ---
#pragma unroll
    for (int q = 0; q < 8; ++q) {
        u64x2 v = wsrc[((5 * 16 + (half << 3) + q) << 9) + cc];
        wlds[q][tid][0] = v.x;
        wlds[q][tid][1] = v.y;
    }

    // thresholds -> popcount cutoffs:  bit(-1) <=> pre < thr  <=>  acc >= cthr
    int cthr[NFF];
#pragma unroll
    for (int L = 0; L < NFF; ++L) {
        int th = (int)rintf(thr_lat[L * DM + tid]); // round-half-even == jnp.round
        cthr[L] = ((DM - th) >> 1) + 1;
    }

    if (tid < 2 * VOCAB) hbL[tid] = hb[tid];

    // --- init h = sign(initial_lat) into hx[0] ---
    {
        u64 m = __ballot(initial_lat[tid] < 0.0f);
        if (lane == 0) hx[0][wv] = m;
    }

    // streaming buffer: this thread's column of the current layer
    u64 p[16];
#pragma unroll
    for (int q = 0; q < 8; ++q) {
        u64x2 v = wsrc[((0 * 16 + (half << 3) + q) << 9) + cc];
        p[2 * q] = v.x; p[2 * q + 1] = v.y;
    }
    __syncthreads(); // one-time full barrier (wlds + hx + hbL visible)

    const int* toks = tokens + b * TSTEPS;
    double lacc = 0.0;

    for (int t = 0; t < TSTEPS; ++t) {
        const int tok = toks[t]; // uniform -> scalar load
        u64 enew = 0;
        if (wv == 0 && lane < 2) enew = eb[tok * 2 + lane]; // prefetch for splice

        SLAYER(0, 1);
        SLAYER(1, 2);
        SLAYER(2, 3);
        SLAYER(3, 4);
        SLAYER(4, 0);   // re-issues layer 0 for step t+1

        // --- layer 5 from LDS: h in hx[1] -> hx[0] ---
        {
            const ulonglong2* hp = (const ulonglong2*)hx[1];
            int acc = 0;
#pragma unroll
            for (int q = 0; q < 8; ++q) {
                ulonglong2 hv = hp[q];                        // broadcast
                ulonglong2 w  = *(const ulonglong2*)wlds[q][tid];
                acc += __popcll(hv.x ^ w.x) + __popcll(hv.y ^ w.y);
            }
            u64 m = __ballot(acc >= cthr[5]);
            if (lane == 0) hx[0][wv] = m;
            BARRIER();
        }

        // --- head + log-softmax + loss + embed splice (wave 0); h5 in hx[0] ---
        if (wv == 0) {
            u64 ra = hx[0][14], rb = hx[0][15];
            u64 h0a = hbL[lane * 2 + 0],        h0b = hbL[lane * 2 + 1];
            u64 h1a = hbL[(lane + 64) * 2 + 0], h1b = hbL[(lane + 64) * 2 + 1];
            int d0 = 128 - 2 * (__popcll(ra ^ h0a) + __popcll(rb ^ h0b));
            int d1 = 128 - 2 * (__popcll(ra ^ h1a) + __popcll(rb ^ h1b));
            float l0 = (float)d0 * (1.0f / 16.0f);
            float l1 = (float)d1 * (1.0f / 16.0f);
            float mx = fmaxf(l0, l1);
#pragma unroll
            for (int sh = 32; sh >= 1; sh >>= 1) mx = fmaxf(mx, __shfl_xor(mx, sh));
            float se = __expf(l0 - mx) + __expf(l1 - mx);
#pragma unroll
            for (int sh = 32; sh >= 1; sh >>= 1) se += __shfl_xor(se, sh);
            int   tl   = tok & 63;
            float la   = __shfl(l0, tl);
            float lb   = __shfl(l1, tl);
            float ltok = (tok >> 6) ? lb : la;
            lacc += (double)(mx + __logf(se) - ltok);
            // splice x_new read-part = sign(embed[tok]) into words 14,15
            if (lane < 2) hx[0][14 + lane] = enew;
        }
        BARRIER();
    }

    if (tid == 0) losses[b] = lacc;
}

__global__ void reduce_loss(const double* __restrict__ losses, float* __restrict__ out) {
    int lane = threadIdx.x; // 64 threads, 1 wave
    double v = losses[lane];
#pragma unroll
    for (int sh = 32; sh >= 1; sh >>= 1) v += __shfl_down(v, sh);
    if (lane == 0) out[0] = (float)(v * (1.0 / ((double)BATCH * (double)TSTEPS)));
}

extern "C" void kernel_launch(void* const* d_in, const int* in_sizes, int n_in,
                              void* d_out, int out_size, void* d_ws, size_t ws_size,
                              hipStream_t stream) {
    const int*   tokens  = (const int*)d_in[0];   // (64, 512) int32
    const float* initial = (const float*)d_in[1]; // (1024,)
    const float* embed   = (const float*)d_in[2]; // (128, 128)
    const float* ff      = (const float*)d_in[3]; // (6, 1024, 1024)
    const float* head    = (const float*)d_in[4]; // (128, 128)
    const float* thrl    = (const float*)d_in[5]; // (6, 1024)

    char* ws = (char*)d_ws;
    u64*    ffs    = (u64*)ws;                 // 786432 B
    u64*    eb     = (u64*)(ws + OFF_EB);      // 2048 B
    u64*    hb     = (u64*)(ws + OFF_HB);      // 2048 B
    double* losses = (double*)(ws + OFF_LOSS); // 512 B

    pack_ff<<<384, 256, 0, stream>>>(ff, ffs);
    pack_small<<<1, 256, 0, stream>>>(embed, head, eb, hb);
    brnn_main<<<BATCH, 1024, 0, stream>>>(tokens, initial, thrl, ffs, eb, hb, losses);
    reduce_loss<<<1, 64, 0, stream>>>(losses, (float*)d_out);
}